// Round 5
// baseline (475.069 us; speedup 1.0000x reference)
//
#include <hip/hip_runtime.h>

// B=2, S=2048, D=2048, H=16, KV=8, HD=128, N_REP=2.
// I/O: fp32. Compute: bf16 MFMA, fp32 accum.
//
// Pipeline (6 dispatches):
//   1. prep: cvt x->bf16, transpose Wq/Wk/Wv->WqkvT, Wo->WoT, zero steal-counter
//   2. gemm_bt: QKV = xb @ WqkvT  (xor-swizzled LDS, conflict-free)
//   3. rope (Q and K parts)
//   4. transpose V part per-batch -> Vt[b][kv*128+hd][s]
//   5. flash v3: work-steal, q-tile 128, dbuf K/V, 1 barrier/tile, ones-MFMA row sums
//   6. gemm_bt: out = Ab @ WoT -> d_out (fp32)

typedef __bf16 bf16;
typedef __bf16 bf16x4 __attribute__((ext_vector_type(4)));
typedef __bf16 bf16x8 __attribute__((ext_vector_type(8)));
typedef float floatx4 __attribute__((ext_vector_type(4)));

#define AS1(p) ((const __attribute__((address_space(1))) void*)(p))
#define AS3(p) ((__attribute__((address_space(3))) void*)(p))

__device__ __forceinline__ void load16(const void* g, void* l) {
  __builtin_amdgcn_global_load_lds(AS1(g), AS3(l), 16, 0, 0);
}

// ---------------- prep: x convert + 4 weight transposes + counter zero ----------------
__global__ __launch_bounds__(256) void prep_kernel(
    const float* __restrict__ x, const float* __restrict__ Wq,
    const float* __restrict__ Wk, const float* __restrict__ Wv,
    const float* __restrict__ Wo, bf16* __restrict__ xb,
    bf16* __restrict__ WqkvT, bf16* __restrict__ WoT, int* __restrict__ cnt) {
  const int z = blockIdx.z;
  if (z == 4) {  // x fp32 -> bf16, 2 float4 per thread; also zero steal counter
    int bid = blockIdx.y * 64 + blockIdx.x;
    if (bid == 0 && threadIdx.x == 0) cnt[0] = 0;
    int i = bid * 256 + threadIdx.x;
#pragma unroll
    for (int rep = 0; rep < 2; rep++) {
      int idx = i + rep * 1048576;
      float4 v = ((const float4*)x)[idx];
      bf16x4 o = {(bf16)v.x, (bf16)v.y, (bf16)v.z, (bf16)v.w};
      ((bf16x4*)xb)[idx] = o;
    }
    return;
  }
  __shared__ float tile[32][33];
  const float* src = z == 0 ? Wq : z == 1 ? Wk : z == 2 ? Wv : Wo;
  bf16* dst = z == 0 ? WqkvT
            : z == 1 ? WqkvT + 2048ull * 2048
            : z == 2 ? WqkvT + 3072ull * 2048
                     : WoT;
  const int ncols = (z == 1 || z == 2) ? 1024 : 2048;
  const int c0 = blockIdx.x * 32, r0 = blockIdx.y * 32;
  if (c0 >= ncols) return;
  const int tx = threadIdx.x & 31, ty = threadIdx.x >> 5;  // 32 x 8
#pragma unroll
  for (int i = 0; i < 4; i++) {
    int ri = ty + i * 8;
    tile[ri][tx] = src[(long)(r0 + ri) * ncols + c0 + tx];
  }
  __syncthreads();
#pragma unroll
  for (int i = 0; i < 4; i++) {
    int ci = ty + i * 8;
    dst[(long)(c0 + ci) * 2048 + r0 + tx] = (bf16)tile[tx][ci];
  }
}

// ---------------- bf16 tiled transpose (for V) ----------------
__global__ __launch_bounds__(256) void transpose_bf16(
    const bf16* __restrict__ in, bf16* __restrict__ out,
    int ldi, int ldo, long ibs, long obs) {
  __shared__ bf16 tile[32][33];
  const long ib = ibs * blockIdx.z, ob = obs * blockIdx.z;
  const int c0 = blockIdx.x * 32, r0 = blockIdx.y * 32;
  const int tx = threadIdx.x & 31, ty = threadIdx.x >> 5;
#pragma unroll
  for (int i = 0; i < 4; i++) {
    int ri = ty + i * 8;
    tile[ri][tx] = in[ib + (long)(r0 + ri) * ldi + c0 + tx];
  }
  __syncthreads();
#pragma unroll
  for (int i = 0; i < 4; i++) {
    int ci = ty + i * 8;
    out[ob + (long)(c0 + ci) * ldo + r0 + tx] = tile[tx][ci];
  }
}

// ---------------- GEMM: C[M,N] = A[M,K] * Bt[N,K]^T, bf16 in, CT out ----------------
// LDS tiles 128 rows x 32 cols; 4 chunks of 16B per row, chunk xor-swizzled by
// (row>>1)&3 so ds_read_b128 lanes spread over all 8 bank-groups (conflict-free).
template <typename CT>
__global__ __launch_bounds__(256) void gemm_bt(
    const bf16* __restrict__ A, const bf16* __restrict__ Bt, CT* __restrict__ C,
    int M, int N, int K) {
  __shared__ bf16 As[128 * 32];
  __shared__ bf16 Bs[128 * 32];
  const int tid = threadIdx.x;
  const int lane = tid & 63, quad = lane >> 4, l16 = lane & 15;
  const int wave = tid >> 6;
  const int wbase = tid & ~63;
  const int m0 = blockIdx.y * 128, n0 = blockIdx.x * 128;
  const int wm = (wave & 1) * 64, wn = (wave >> 1) * 64;
  floatx4 acc[4][4] = {};
  for (int k0 = 0; k0 < K; k0 += 32) {
    __syncthreads();
#pragma unroll
    for (int u = 0; u < 2; u++) {
      int g = u * 256 + tid;
      int row = g >> 2, cc = (g & 3) ^ ((row >> 1) & 3);  // source chunk for swizzled slot
      const bf16* ga = A + (size_t)(m0 + row) * K + k0 + cc * 8;
      const bf16* gb = Bt + (size_t)(n0 + row) * K + k0 + cc * 8;
      load16(ga, (char*)As + (u * 256 + wbase) * 16);
      load16(gb, (char*)Bs + (u * 256 + wbase) * 16);
    }
    __syncthreads();
    bf16x8 af[4], bg[4];
#pragma unroll
    for (int i = 0; i < 4; i++) {
      int ar = wm + i * 16 + l16;
      af[i] = *(const bf16x8*)(As + ar * 32 + ((quad ^ ((ar >> 1) & 3)) * 8));
    }
#pragma unroll
    for (int j = 0; j < 4; j++) {
      int br = wn + j * 16 + l16;
      bg[j] = *(const bf16x8*)(Bs + br * 32 + ((quad ^ ((br >> 1) & 3)) * 8));
    }
#pragma unroll
    for (int i = 0; i < 4; i++)
#pragma unroll
      for (int j = 0; j < 4; j++)
        acc[i][j] = __builtin_amdgcn_mfma_f32_16x16x32_bf16(af[i], bg[j], acc[i][j], 0, 0, 0);
  }
#pragma unroll
  for (int i = 0; i < 4; i++)
#pragma unroll
    for (int j = 0; j < 4; j++)
#pragma unroll
      for (int r = 0; r < 4; r++) {
        int row = m0 + wm + i * 16 + quad * 4 + r;
        int col = n0 + wn + j * 16 + l16;
        C[(size_t)row * N + col] = (CT)acc[i][j][r];
      }
}

// ---------------- RoPE, Q part + K part in one launch ----------------
__global__ void rope_kernel(bf16* __restrict__ QKV, const float* __restrict__ cosb,
                            const float* __restrict__ sinb) {
  int idx = blockIdx.x * blockDim.x + threadIdx.x;
  if (idx >= 6291456) return;
  int nh, nhs, offc;
  if (idx < 4194304) { nh = 16; nhs = 4; offc = 0; }
  else { idx -= 4194304; nh = 8; nhs = 3; offc = 2048; }
  int d = idx & 63;
  int rest = idx >> 6;
  int hh = rest & (nh - 1);
  int bs = rest >> nhs;  // b*2048 + s
  int s = bs & 2047;
  size_t base = (size_t)bs * 4096 + offc + hh * 128;
  float c0 = cosb[s * 128 + d];
  float c1 = cosb[s * 128 + d + 64];
  float s0 = sinb[s * 128 + d];
  float s1 = sinb[s * 128 + d + 64];
  float x0 = (float)QKV[base + d];
  float x1 = (float)QKV[base + d + 64];
  QKV[base + d] = (bf16)(x0 * c0 - x1 * s0);
  QKV[base + d + 64] = (bf16)(x1 * c1 + x0 * s1);
}

// ---------------- Flash v3 ----------------
// Items: w in [0,512): qt = 15-(w>>5) (LPT), b=(w>>4)&1, h=w&15. Q-tile 128 rows.
// Block = 256 thr (4 waves x 32 q-rows). K-tile 64 keys, double-buffered.
// LDS (72 KB + wsh):
//   buf0: K [64 key][128 hd] swz&15 @0      V [128 hd][64 key] swz&7 @16K
//   buf1: same @32K/@48K
//   P: 4 waves x [32 q][32 key] swz        @64K (8 KB; used in 2 key-halves)
// One barrier per tile: barrier drains buf[cur] loads; prefetch buf[nxt] issued
// right after, lands during compute. Max-free softmax; row sums via ones-MFMA.

template <bool MASK>
__device__ __forceinline__ void attn_tile(
    const bf16* Ksw, const bf16* Vsw, bf16* Pw, const bf16x8 (&aq)[2][4],
    const bf16x8& ones, floatx4 (&oacc)[2][8], floatx4 (&lacc)[2],
    int k0, int q0w, int l16, int quad) {
  floatx4 sacc[2][4] = {};
#pragma unroll
  for (int ks = 0; ks < 4; ks++) {
#pragma unroll
    for (int j = 0; j < 4; j++) {
      int row = j * 16 + l16;
      bf16x8 bk = *(const bf16x8*)(Ksw + row * 128 + (((ks * 4 + quad) ^ (row & 15)) * 8));
      sacc[0][j] = __builtin_amdgcn_mfma_f32_16x16x32_bf16(aq[0][ks], bk, sacc[0][j], 0, 0, 0);
      sacc[1][j] = __builtin_amdgcn_mfma_f32_16x16x32_bf16(aq[1][ks], bk, sacc[1][j], 0, 0, 0);
    }
  }
  const float C = 0.12752188659023044f;  // (1/sqrt(128)) * log2(e)
#pragma unroll
  for (int half = 0; half < 2; half++) {
    // write P for keys [half*32, half*32+32) into per-wave 32x32 region
#pragma unroll
    for (int i = 0; i < 2; i++)
#pragma unroll
      for (int r = 0; r < 4; r++) {
        int row = i * 16 + quad * 4 + r;
#pragma unroll
        for (int jj = 0; jj < 2; jj++) {
          int j = half * 2 + jj;
          float p = exp2f(sacc[i][j][r] * C);
          if (MASK) {
            int key = k0 + j * 16 + l16;
            if (key > q0w + row) p = 0.f;
          }
          int kk = jj * 16 + l16;
          Pw[row * 32 + (((kk >> 3) ^ ((row >> 1) & 3)) * 8) + (kk & 7)] = (bf16)p;
        }
      }
    bf16x8 ap0 = *(const bf16x8*)(Pw + l16 * 32 + ((quad ^ ((l16 >> 1) & 3)) * 8));
    bf16x8 ap1 = *(const bf16x8*)(Pw + (16 + l16) * 32 + ((quad ^ ((l16 >> 1) & 3)) * 8));
    lacc[0] = __builtin_amdgcn_mfma_f32_16x16x32_bf16(ap0, ones, lacc[0], 0, 0, 0);
    lacc[1] = __builtin_amdgcn_mfma_f32_16x16x32_bf16(ap1, ones, lacc[1], 0, 0, 0);
#pragma unroll
    for (int j = 0; j < 8; j++) {
      int vr = j * 16 + l16;
      bf16x8 bv = *(const bf16x8*)(Vsw + vr * 64 + (((half * 4 + quad) ^ (vr & 7)) * 8));
      oacc[0][j] = __builtin_amdgcn_mfma_f32_16x16x32_bf16(ap0, bv, oacc[0][j], 0, 0, 0);
      oacc[1][j] = __builtin_amdgcn_mfma_f32_16x16x32_bf16(ap1, bv, oacc[1][j], 0, 0, 0);
    }
  }
}

__global__ __launch_bounds__(256, 2) void flash_kernel(
    const bf16* __restrict__ QKV, const bf16* __restrict__ Vt, bf16* __restrict__ O,
    int* __restrict__ cnt) {
  __shared__ char smem[73728];  // 64K dbuf + 8K P
  __shared__ int wsh;
  const int tid = threadIdx.x;
  const int wave = tid >> 6, lane = tid & 63, quad = lane >> 4, l16 = lane & 15;
  const int wbase = tid & ~63;
  bf16* Pw = (bf16*)(smem + 65536) + wave * 1024;
  bf16x8 ones;
#pragma unroll
  for (int e = 0; e < 8; e++) ones[e] = (bf16)1.0f;

  for (;;) {
    if (tid == 0) wsh = atomicAdd(cnt, 1);
    __syncthreads();  // publish wsh; prior item's compute fully done
    const int w = wsh;
    if (w >= 512) break;
    const int qt = 15 - (w >> 5);
    const int b = (w >> 4) & 1, h = w & 15, kvh = h >> 1;
    const int q0 = qt * 128;

    auto stage_kv = [&](int kt, int buf) {
      char* Kd = smem + buf * 32768;
      char* Vd = Kd + 16384;
#pragma unroll
      for (int u = 0; u < 4; u++) {
        int g = u * 256 + tid;
        int row = g >> 4, cc = (g & 15) ^ (row & 15);
        const bf16* gp = QKV + (size_t)(b * 2048 + kt * 64 + row) * 4096 + 2048 +
                         kvh * 128 + cc * 8;
        load16(gp, Kd + (u * 256 + wbase) * 16);
      }
#pragma unroll
      for (int u = 0; u < 4; u++) {
        int g = u * 256 + tid;
        int row = g >> 3, cc = (g & 7) ^ (row & 7);
        const bf16* gp = Vt + (size_t)(b * 1024 + kvh * 128 + row) * 2048 + kt * 64 + cc * 8;
        load16(gp, Vd + (u * 256 + wbase) * 16);
      }
    };

    // stage Q [128 q][128 hd] into smem[0..32K), chunk-swizzled by row&15
#pragma unroll
    for (int u = 0; u < 8; u++) {
      int g = u * 256 + tid;
      int row = g >> 4, cc = (g & 15) ^ (row & 15);
      const bf16* gp = QKV + (size_t)(b * 2048 + q0 + row) * 4096 + h * 128 + cc * 8;
      load16(gp, smem + (u * 256 + wbase) * 16);
    }
    __syncthreads();  // Q staged
    bf16x8 aq[2][4];
#pragma unroll
    for (int i = 0; i < 2; i++)
#pragma unroll
      for (int ks = 0; ks < 4; ks++) {
        int row = wave * 32 + i * 16 + l16;
        aq[i][ks] =
            *(const bf16x8*)((bf16*)smem + row * 128 + (((ks * 4 + quad) ^ (row & 15)) * 8));
      }
    __syncthreads();  // all waves extracted Q before buf0 overwrites it
    stage_kv(0, 0);

    floatx4 oacc[2][8] = {};
    floatx4 lacc[2] = {};
    const int q0w = q0 + wave * 32;
    const int nkt = 2 * qt + 2;

    for (int kt = 0; kt < nkt; kt++) {
      __syncthreads();  // drains vmcnt: buf[cur] ready; prior reads of buf[nxt] done
      const int cur = kt & 1;
      if (kt + 1 < nkt) stage_kv(kt + 1, 1 - cur);  // prefetch during compute
      const bf16* Ksw = (const bf16*)(smem + cur * 32768);
      const bf16* Vsw = (const bf16*)(smem + cur * 32768 + 16384);
      if (kt >= 2 * qt)
        attn_tile<true>(Ksw, Vsw, Pw, aq, ones, oacc, lacc, kt * 64, q0w, l16, quad);
      else
        attn_tile<false>(Ksw, Vsw, Pw, aq, ones, oacc, lacc, kt * 64, q0w, l16, quad);
    }

    // epilogue: O = oacc / rowsum (lacc holds the row sum in every column)
    float rl[2][4];
#pragma unroll
    for (int i = 0; i < 2; i++)
#pragma unroll
      for (int r = 0; r < 4; r++) rl[i][r] = 1.0f / lacc[i][r];
#pragma unroll
    for (int i = 0; i < 2; i++)
#pragma unroll
      for (int j = 0; j < 8; j++)
#pragma unroll
        for (int r = 0; r < 4; r++) {
          int s = q0w + i * 16 + quad * 4 + r;
          O[(size_t)(b * 2048 + s) * 2048 + h * 128 + j * 16 + l16] =
              (bf16)(oacc[i][j][r] * rl[i][r]);
        }
  }
}

extern "C" void kernel_launch(void* const* d_in, const int* in_sizes, int n_in,
                              void* d_out, int out_size, void* d_ws, size_t ws_size,
                              hipStream_t stream) {
  (void)in_sizes; (void)n_in; (void)out_size; (void)ws_size;
  const float* x    = (const float*)d_in[0];
  const float* cosb = (const float*)d_in[1];
  const float* sinb = (const float*)d_in[2];
  const float* Wq   = (const float*)d_in[3];
  const float* Wk   = (const float*)d_in[4];
  const float* Wv   = (const float*)d_in[5];
  const float* Wo   = (const float*)d_in[6];
  float* out = (float*)d_out;

  char* ws = (char*)d_ws;
  size_t off = 0;
  auto alloc = [&](size_t bytes) { void* p = ws + off; off += bytes; return p; };
  bf16* xb    = (bf16*)alloc(4096ull * 2048 * 2);  // 16 MB
  bf16* WqkvT = (bf16*)alloc(4096ull * 2048 * 2);  // 16 MB  [Wq^T | Wk^T | Wv^T]
  bf16* WoT   = (bf16*)alloc(2048ull * 2048 * 2);  //  8 MB
  bf16* QKV   = (bf16*)alloc(4096ull * 4096 * 2);  // 32 MB  [s][Q 2048 | K 1024 | V 1024]
  bf16* Vtb   = (bf16*)alloc(2048ull * 2048 * 2);  //  8 MB  [b][kv*128+hd][s]
  bf16* Ab    = (bf16*)alloc(4096ull * 2048 * 2);  // 16 MB
  int*  cnt   = (int*)alloc(256);                  // work-steal counter

  // 1. prep: x->bf16, weight transposes, zero counter
  prep_kernel<<<dim3(64, 64, 5), 256, 0, stream>>>(x, Wq, Wk, Wv, Wo, xb, WqkvT, WoT, cnt);

  // 2. fused QKV projection: [4096 s] x [4096 n]
  gemm_bt<bf16><<<dim3(32, 32), 256, 0, stream>>>(xb, WqkvT, QKV, 4096, 4096, 2048);

  // 3. RoPE on Q and K parts
  rope_kernel<<<24576, 256, 0, stream>>>(QKV, cosb, sinb);

  // 4. V transpose per batch: [2048 s][1024 c] -> [1024 c][2048 s]
  transpose_bf16<<<dim3(32, 64, 2), 256, 0, stream>>>(
      QKV + 3072, Vtb, 4096, 2048, 2048ll * 4096, 1024ll * 2048);

  // 5. flash attention, work-stealing, double-buffered
  flash_kernel<<<dim3(512, 1, 1), 256, 0, stream>>>(QKV, Vtb, Ab, cnt);

  // 6. output projection -> fp32 out
  gemm_bt<float><<<dim3(16, 32), 256, 0, stream>>>(Ab, WoT, out, 4096, 2048, 2048);
}

// Round 6
// 417.025 us; speedup vs baseline: 1.1392x; 1.1392x over previous
//
#include <hip/hip_runtime.h>

// B=2, S=2048, D=2048, H=16, KV=8, HD=128, N_REP=2.
// I/O: fp32. Compute: bf16 MFMA, fp32 accum.
//
// Pipeline (5 dispatches):
//   1. prep: cvt x->bf16, transpose Wq/Wk/Wv->WqkvT, Wo->WoT, zero steal-counter
//   2. gemm_bt<ROPE>: QKV = xb @ WqkvT, rope fused in epilogue for cols < 3072
//   3. transpose V part per-batch -> Vt[b][kv*128+hd][s]
//   4. flash (round-4 proven version): work-steal 1024 LPT items, 128-thr blocks,
//      40 KB LDS, ones-MFMA row sums, max-free softmax
//   5. gemm_bt: out = Ab @ WoT -> d_out (fp32)

typedef __bf16 bf16;
typedef __bf16 bf16x4 __attribute__((ext_vector_type(4)));
typedef __bf16 bf16x8 __attribute__((ext_vector_type(8)));
typedef float floatx4 __attribute__((ext_vector_type(4)));

#define AS1(p) ((const __attribute__((address_space(1))) void*)(p))
#define AS3(p) ((__attribute__((address_space(3))) void*)(p))

__device__ __forceinline__ void load16(const void* g, void* l) {
  __builtin_amdgcn_global_load_lds(AS1(g), AS3(l), 16, 0, 0);
}

// ---------------- prep: x convert + 4 weight transposes + counter zero ----------------
__global__ __launch_bounds__(256) void prep_kernel(
    const float* __restrict__ x, const float* __restrict__ Wq,
    const float* __restrict__ Wk, const float* __restrict__ Wv,
    const float* __restrict__ Wo, bf16* __restrict__ xb,
    bf16* __restrict__ WqkvT, bf16* __restrict__ WoT, int* __restrict__ cnt) {
  const int z = blockIdx.z;
  if (z == 4) {  // x fp32 -> bf16, 2 float4 per thread; also zero steal counter
    int bid = blockIdx.y * 64 + blockIdx.x;
    if (bid == 0 && threadIdx.x == 0) cnt[0] = 0;
    int i = bid * 256 + threadIdx.x;
#pragma unroll
    for (int rep = 0; rep < 2; rep++) {
      int idx = i + rep * 1048576;
      float4 v = ((const float4*)x)[idx];
      bf16x4 o = {(bf16)v.x, (bf16)v.y, (bf16)v.z, (bf16)v.w};
      ((bf16x4*)xb)[idx] = o;
    }
    return;
  }
  __shared__ float tile[32][33];
  const float* src = z == 0 ? Wq : z == 1 ? Wk : z == 2 ? Wv : Wo;
  bf16* dst = z == 0 ? WqkvT
            : z == 1 ? WqkvT + 2048ull * 2048
            : z == 2 ? WqkvT + 3072ull * 2048
                     : WoT;
  const int ncols = (z == 1 || z == 2) ? 1024 : 2048;
  const int c0 = blockIdx.x * 32, r0 = blockIdx.y * 32;
  if (c0 >= ncols) return;
  const int tx = threadIdx.x & 31, ty = threadIdx.x >> 5;  // 32 x 8
#pragma unroll
  for (int i = 0; i < 4; i++) {
    int ri = ty + i * 8;
    tile[ri][tx] = src[(long)(r0 + ri) * ncols + c0 + tx];
  }
  __syncthreads();
#pragma unroll
  for (int i = 0; i < 4; i++) {
    int ci = ty + i * 8;
    dst[(long)(c0 + ci) * 2048 + r0 + tx] = (bf16)tile[tx][ci];
  }
}

// ---------------- bf16 tiled transpose (for V) ----------------
__global__ __launch_bounds__(256) void transpose_bf16(
    const bf16* __restrict__ in, bf16* __restrict__ out,
    int ldi, int ldo, long ibs, long obs) {
  __shared__ bf16 tile[32][33];
  const long ib = ibs * blockIdx.z, ob = obs * blockIdx.z;
  const int c0 = blockIdx.x * 32, r0 = blockIdx.y * 32;
  const int tx = threadIdx.x & 31, ty = threadIdx.x >> 5;
#pragma unroll
  for (int i = 0; i < 4; i++) {
    int ri = ty + i * 8;
    tile[ri][tx] = in[ib + (long)(r0 + ri) * ldi + c0 + tx];
  }
  __syncthreads();
#pragma unroll
  for (int i = 0; i < 4; i++) {
    int ci = ty + i * 8;
    out[ob + (long)(c0 + ci) * ldo + r0 + tx] = tile[tx][ci];
  }
}

// ---------------- GEMM: C[M,N] = A[M,K] * Bt[N,K]^T, bf16 in, CT out ----------------
// Wave tile 32 rows x 128 cols (acc[2][8]) so each head's 128 cols sit in one wave:
// ROPE fuses rotary embedding in the epilogue (partner col = c^64 -> acc[i][j^4][r]).
// LDS chunk xor-swizzle by (row>>1)&3 keeps ds_read_b128 conflict-free.
template <typename CT, bool ROPE>
__global__ __launch_bounds__(256) void gemm_bt(
    const bf16* __restrict__ A, const bf16* __restrict__ Bt, CT* __restrict__ C,
    int M, int N, int K, const float* __restrict__ cosb, const float* __restrict__ sinb) {
  __shared__ bf16 As[128 * 32];
  __shared__ bf16 Bs[128 * 32];
  const int tid = threadIdx.x;
  const int lane = tid & 63, quad = lane >> 4, l16 = lane & 15;
  const int wave = tid >> 6;
  const int wbase = tid & ~63;
  const int m0 = blockIdx.y * 128, n0 = blockIdx.x * 128;
  const int wm = wave * 32;
  floatx4 acc[2][8] = {};
  for (int k0 = 0; k0 < K; k0 += 32) {
    __syncthreads();
#pragma unroll
    for (int u = 0; u < 2; u++) {
      int g = u * 256 + tid;
      int row = g >> 2, cc = (g & 3) ^ ((row >> 1) & 3);  // source chunk for swizzled slot
      const bf16* ga = A + (size_t)(m0 + row) * K + k0 + cc * 8;
      const bf16* gb = Bt + (size_t)(n0 + row) * K + k0 + cc * 8;
      load16(ga, (char*)As + (u * 256 + wbase) * 16);
      load16(gb, (char*)Bs + (u * 256 + wbase) * 16);
    }
    __syncthreads();
    bf16x8 af[2], bg[8];
#pragma unroll
    for (int i = 0; i < 2; i++) {
      int ar = wm + i * 16 + l16;
      af[i] = *(const bf16x8*)(As + ar * 32 + ((quad ^ ((ar >> 1) & 3)) * 8));
    }
#pragma unroll
    for (int j = 0; j < 8; j++) {
      int br = j * 16 + l16;
      bg[j] = *(const bf16x8*)(Bs + br * 32 + ((quad ^ ((br >> 1) & 3)) * 8));
    }
#pragma unroll
    for (int i = 0; i < 2; i++)
#pragma unroll
      for (int j = 0; j < 8; j++)
        acc[i][j] = __builtin_amdgcn_mfma_f32_16x16x32_bf16(af[i], bg[j], acc[i][j], 0, 0, 0);
  }
  const bool do_rope = ROPE && (n0 < 3072);
#pragma unroll
  for (int i = 0; i < 2; i++)
#pragma unroll
    for (int j = 0; j < 8; j++) {
      int col = j * 16 + l16;  // also head-dim d, since n0 % 128 == 0
#pragma unroll
      for (int r = 0; r < 4; r++) {
        int row = m0 + wm + i * 16 + quad * 4 + r;
        float v = acc[i][j][r];
        if (do_rope) {
          int s = row & 2047;
          float partner = acc[i][j ^ 4][r];
          float sgn = (col < 64) ? -1.0f : 1.0f;
          v = v * cosb[s * 128 + col] + sgn * partner * sinb[s * 128 + col];
        }
        C[(size_t)row * N + n0 + col] = (CT)v;
      }
    }
}

// ---------------- Flash (round-4 proven): work-stealing ----------------
// Items: w in [0,1024): qt64 = 31 - (w>>5) (longest-first), b = (w>>4)&1, h = w&15.
// Block = 128 threads (2 waves x 32 q-rows). K-tile = 64 keys.
// LDS: Ksw [64 key][128 hd] swz&15 (also Q staging)  16 KB @ 0
//      Vsw [128 hd][64 key] swz&7                    16 KB @ 16K
//      P   [wave][32 q][64 k] swz&7                   8 KB @ 32K
// Row sums via ones-MFMA into lacc (C-layout, matches oacc). Max-free softmax.

template <bool MASK>
__device__ __forceinline__ void attn_tile64(
    const bf16* Ksw, const bf16* Vsw, bf16* Pw, const bf16x8 (&aq)[2][4],
    const bf16x8& ones, floatx4 (&oacc)[2][8], floatx4 (&lacc)[2],
    int k0, int q0w, int l16, int quad) {
  floatx4 sacc[2][4] = {};
#pragma unroll
  for (int ks = 0; ks < 4; ks++) {
#pragma unroll
    for (int j = 0; j < 4; j++) {
      int row = j * 16 + l16;
      bf16x8 bk = *(const bf16x8*)(Ksw + row * 128 + (((ks * 4 + quad) ^ (row & 15)) * 8));
      sacc[0][j] = __builtin_amdgcn_mfma_f32_16x16x32_bf16(aq[0][ks], bk, sacc[0][j], 0, 0, 0);
      sacc[1][j] = __builtin_amdgcn_mfma_f32_16x16x32_bf16(aq[1][ks], bk, sacc[1][j], 0, 0, 0);
    }
  }
  const float C = 0.12752188659023044f;  // (1/sqrt(128)) * log2(e)
#pragma unroll
  for (int i = 0; i < 2; i++)
#pragma unroll
    for (int r = 0; r < 4; r++) {
      int row = i * 16 + quad * 4 + r;
#pragma unroll
      for (int j = 0; j < 4; j++) {
        float p = exp2f(sacc[i][j][r] * C);
        if (MASK) {
          int key = k0 + j * 16 + l16;
          int qi = q0w + row;
          if (key > qi) p = 0.f;
        }
        int col = j * 16 + l16;
        Pw[row * 64 + (((col >> 3) ^ (row & 7)) * 8) + (col & 7)] = (bf16)p;
      }
    }
#pragma unroll
  for (int ks = 0; ks < 2; ks++) {
    bf16x8 ap0 = *(const bf16x8*)(Pw + l16 * 64 + (((ks * 4 + quad) ^ (l16 & 7)) * 8));
    bf16x8 ap1 = *(const bf16x8*)(Pw + (16 + l16) * 64 + (((ks * 4 + quad) ^ (l16 & 7)) * 8));
    lacc[0] = __builtin_amdgcn_mfma_f32_16x16x32_bf16(ap0, ones, lacc[0], 0, 0, 0);
    lacc[1] = __builtin_amdgcn_mfma_f32_16x16x32_bf16(ap1, ones, lacc[1], 0, 0, 0);
#pragma unroll
    for (int j = 0; j < 8; j++) {
      int vr = j * 16 + l16;
      bf16x8 bv = *(const bf16x8*)(Vsw + vr * 64 + (((ks * 4 + quad) ^ (vr & 7)) * 8));
      oacc[0][j] = __builtin_amdgcn_mfma_f32_16x16x32_bf16(ap0, bv, oacc[0][j], 0, 0, 0);
      oacc[1][j] = __builtin_amdgcn_mfma_f32_16x16x32_bf16(ap1, bv, oacc[1][j], 0, 0, 0);
    }
  }
}

__global__ __launch_bounds__(128) void flash_kernel(
    const bf16* __restrict__ QKV, const bf16* __restrict__ Vt, bf16* __restrict__ O,
    int* __restrict__ cnt) {
  __shared__ char smem[40960];
  __shared__ int wsh;
  bf16* Ksw = (bf16*)smem;
  bf16* Vsw = (bf16*)(smem + 16384);
  const int tid = threadIdx.x;
  const int wave = tid >> 6, lane = tid & 63, quad = lane >> 4, l16 = lane & 15;
  const int wbase = tid & ~63;
  bf16* Pw = (bf16*)(smem + 32768) + wave * 2048;
  bf16x8 ones;
#pragma unroll
  for (int e = 0; e < 8; e++) ones[e] = (bf16)1.0f;

  for (;;) {
    if (tid == 0) wsh = atomicAdd(cnt, 1);
    __syncthreads();  // publish wsh; also guards prior item's LDS reads
    const int w = wsh;
    if (w >= 1024) break;
    const int qt = 31 - (w >> 5);
    const int b = (w >> 4) & 1, h = w & 15, kvh = h >> 1;
    const int q0 = qt * 64;

    // stage Q tile [64 q][128 hd] into Ksw region, chunk-swizzled by row&15
#pragma unroll
    for (int u = 0; u < 8; u++) {
      int g = u * 128 + tid;
      int row = g >> 4, cc = g & 15;
      const bf16* gp = QKV + (size_t)(b * 2048 + q0 + row) * 4096 + h * 128 +
                       ((cc ^ (row & 15)) * 8);
      load16(gp, smem + (u * 128 + wbase) * 16);
    }
    __syncthreads();
    bf16x8 aq[2][4];
#pragma unroll
    for (int i = 0; i < 2; i++)
#pragma unroll
      for (int ks = 0; ks < 4; ks++) {
        int row = wave * 32 + i * 16 + l16;
        aq[i][ks] =
            *(const bf16x8*)((bf16*)smem + row * 128 + (((ks * 4 + quad) ^ (row & 15)) * 8));
      }

    floatx4 oacc[2][8] = {};
    floatx4 lacc[2] = {};
    const int q0w = q0 + wave * 32;
    const int nkt = qt + 1;

    for (int kt = 0; kt < nkt; kt++) {
      __syncthreads();  // aq extracted (kt=0) / prior tile's K,V,P reads done
      // stage K tile [64 key][128 hd]
#pragma unroll
      for (int u = 0; u < 8; u++) {
        int g = u * 128 + tid;
        int row = g >> 4, cc = g & 15;
        const bf16* gp = QKV + (size_t)(b * 2048 + kt * 64 + row) * 4096 + 2048 +
                         kvh * 128 + ((cc ^ (row & 15)) * 8);
        load16(gp, (char*)Ksw + (u * 128 + wbase) * 16);
      }
      // stage V^T tile [128 hd][64 key]
#pragma unroll
      for (int u = 0; u < 8; u++) {
        int g = u * 128 + tid;
        int row = g >> 3, cc = g & 7;
        const bf16* gp = Vt + (size_t)(b * 1024 + kvh * 128 + row) * 2048 + kt * 64 +
                         ((cc ^ (row & 7)) * 8);
        load16(gp, (char*)Vsw + (u * 128 + wbase) * 16);
      }
      __syncthreads();
      if (kt == qt)
        attn_tile64<true>(Ksw, Vsw, Pw, aq, ones, oacc, lacc, kt * 64, q0w, l16, quad);
      else
        attn_tile64<false>(Ksw, Vsw, Pw, aq, ones, oacc, lacc, kt * 64, q0w, l16, quad);
    }

    // epilogue: O = oacc / rowsum  (lacc has the row sum in every column)
    float rl[2][4];
#pragma unroll
    for (int i = 0; i < 2; i++)
#pragma unroll
      for (int r = 0; r < 4; r++) rl[i][r] = 1.0f / lacc[i][r];
#pragma unroll
    for (int i = 0; i < 2; i++)
#pragma unroll
      for (int j = 0; j < 8; j++)
#pragma unroll
        for (int r = 0; r < 4; r++) {
          int s = q0w + i * 16 + quad * 4 + r;
          O[(size_t)(b * 2048 + s) * 2048 + h * 128 + j * 16 + l16] =
              (bf16)(oacc[i][j][r] * rl[i][r]);
        }
  }
}

extern "C" void kernel_launch(void* const* d_in, const int* in_sizes, int n_in,
                              void* d_out, int out_size, void* d_ws, size_t ws_size,
                              hipStream_t stream) {
  (void)in_sizes; (void)n_in; (void)out_size; (void)ws_size;
  const float* x    = (const float*)d_in[0];
  const float* cosb = (const float*)d_in[1];
  const float* sinb = (const float*)d_in[2];
  const float* Wq   = (const float*)d_in[3];
  const float* Wk   = (const float*)d_in[4];
  const float* Wv   = (const float*)d_in[5];
  const float* Wo   = (const float*)d_in[6];
  float* out = (float*)d_out;

  char* ws = (char*)d_ws;
  size_t off = 0;
  auto alloc = [&](size_t bytes) { void* p = ws + off; off += bytes; return p; };
  bf16* xb    = (bf16*)alloc(4096ull * 2048 * 2);  // 16 MB
  bf16* WqkvT = (bf16*)alloc(4096ull * 2048 * 2);  // 16 MB  [Wq^T | Wk^T | Wv^T]
  bf16* WoT   = (bf16*)alloc(2048ull * 2048 * 2);  //  8 MB
  bf16* QKV   = (bf16*)alloc(4096ull * 4096 * 2);  // 32 MB  [s][Q 2048 | K 1024 | V 1024]
  bf16* Vtb   = (bf16*)alloc(2048ull * 2048 * 2);  //  8 MB  [b][kv*128+hd][s]
  bf16* Ab    = (bf16*)alloc(4096ull * 2048 * 2);  // 16 MB
  int*  cnt   = (int*)alloc(256);                  // work-steal counter

  // 1. prep: x->bf16, weight transposes, zero counter
  prep_kernel<<<dim3(64, 64, 5), 256, 0, stream>>>(x, Wq, Wk, Wv, Wo, xb, WqkvT, WoT, cnt);

  // 2. fused QKV projection + RoPE epilogue: [4096 s] x [4096 n]
  gemm_bt<bf16, true><<<dim3(32, 32), 256, 0, stream>>>(xb, WqkvT, QKV, 4096, 4096, 2048,
                                                        cosb, sinb);

  // 3. V transpose per batch: [2048 s][1024 c] -> [1024 c][2048 s]
  transpose_bf16<<<dim3(32, 64, 2), 256, 0, stream>>>(
      QKV + 3072, Vtb, 4096, 2048, 2048ll * 4096, 1024ll * 2048);

  // 4. flash attention, work-stealing
  flash_kernel<<<dim3(512, 1, 1), 128, 0, stream>>>(QKV, Vtb, Ab, cnt);

  // 5. output projection -> fp32 out
  gemm_bt<float, false><<<dim3(16, 32), 256, 0, stream>>>(Ab, WoT, out, 4096, 2048, 2048,
                                                          nullptr, nullptr);
}